// Round 7
// baseline (627.530 us; speedup 1.0000x reference)
//
#include <hip/hip_runtime.h>
#include <hip/hip_bf16.h>

#define Hn   89
#define Tn   120
#define BM   128
#define LDP  104   // bf16 pitch: 208B rows, 16B-aligned; quad-balanced b128 access
#define NTHR 768   // 12 waves = 6 j-slices x 2 row-halves; grid=256 -> 1 block/CU

using bf16   = __bf16;
using bf16x4 = __attribute__((ext_vector_type(4))) __bf16;
using bf16x8 = __attribute__((ext_vector_type(8))) __bf16;
typedef __attribute__((ext_vector_type(4))) float f32x4;

__device__ __forceinline__ f32x4 ld4(const float* p) {   // 4B-aligned 16B load
  f32x4 v; __builtin_memcpy(&v, p, 16); return v;
}
__device__ __forceinline__ bf16x8 pack8(f32x4 a, f32x4 b) {
  bf16x8 r;
  r[0]=(bf16)a[0]; r[1]=(bf16)a[1]; r[2]=(bf16)a[2]; r[3]=(bf16)a[3];
  r[4]=(bf16)b[0]; r[5]=(bf16)b[1]; r[6]=(bf16)b[2]; r[7]=(bf16)b[3];
  return r;
}
__device__ __forceinline__ float fsig(float x) {
  return __builtin_amdgcn_rcpf(1.f + __builtin_amdgcn_exp2f(-1.44269504f * x));
}
__device__ __forceinline__ float ftanh(float x) {
  return 1.f - 2.f * __builtin_amdgcn_rcpf(1.f + __builtin_amdgcn_exp2f(2.88539008f * x));
}

// Persistent block: 128 rows x 120 steps, 12 waves (6 j-slices x 2 row-halves).
// SWAPPED-OPERAND MFMA: A = weights (M=j), B = X/H tile (N=batch). C/D:
// row=(lane>>4)*4+q = j-offset, col=lane&15 = batch -> each lane owns 4
// CONSECUTIVE j for one batch row: h-write is a single aligned ds_write_b64
// per row-tile (vs 16 scattered b16), H stays plain row-major, no swizzle.
// Biases: X col89==1.0 carries bih+bhh (r,z) and bin (n) on the ih side;
// Whh k>=89 is zero; b_hn applied as a register fma inside the n-gate.
// One barrier/step: { BAR; issue X(t+1); per mt: read frags(buf b), MFMA
// (split ih/hh accs: 3-dep chains), gates, b64 h-write -> buf b^1 };
// commit X(t+1) -> buf b^1 at end.
__global__ __launch_bounds__(NTHR, 3)
void gru_fused(const float* __restrict__ X,    // [B][T][89]
               const float* __restrict__ Wih,  // [267][89]
               const float* __restrict__ Whh,  // [267][89]
               const float* __restrict__ bih,  // [267]
               const float* __restrict__ bhh,  // [267]
               const float* __restrict__ Wm,   // [32][89]
               const float* __restrict__ bm,   // [32]
               const float* __restrict__ Wo,   // [32]
               const float* __restrict__ bo,   // [1]
               float* __restrict__ Y,          // [B] mscore | [B][32] mmetric
               int Bt)
{
  __shared__ __align__(16) bf16 Xl[2][BM][LDP];
  __shared__ __align__(16) bf16 Hl[2][BM][LDP];
  __shared__ float Ml[BM][32];

  const int tid  = threadIdx.x;
  const int lane = tid & 63;
  const int wv   = tid >> 6;       // 0..11
  const int jt   = wv >> 1;        // j-slice 0..5
  const int hf   = wv & 1;         // row half
  const int l15  = lane & 15;
  const int kg   = lane >> 4;      // 0..3
  const int jA   = jt * 16 + l15;  // A-frag row (j) for weight loads
  const bool jAok = (jA < Hn);
  const int j0   = jt * 16 + kg * 4;  // this lane's 4 output j's: j0..j0+3
  const size_t brow0 = (size_t)blockIdx.x * BM;

  // ---- weights -> persistent A-frags; ih k==89 row carries biases ----
  bf16x8 Bf[3][2][3];  // [gate r/z/n][ih/hh][k-tile]
#pragma unroll
  for (int g = 0; g < 3; ++g)
#pragma unroll
    for (int s = 0; s < 2; ++s) {
      const float* W = s ? Whh : Wih;
#pragma unroll
      for (int kt = 0; kt < 3; ++kt) {
        bf16x8 f;
        const int k0 = kt * 32 + kg * 8;
#pragma unroll
        for (int e = 0; e < 8; ++e) {
          const int k = k0 + e;
          float v = 0.f;
          if (jAok) {
            if (k < Hn) v = W[(size_t)(g * Hn + jA) * Hn + k];
            else if (k == Hn && s == 0)   // pairs with X col89 == 1.0
              v = (g < 2) ? (bih[g * Hn + jA] + bhh[g * Hn + jA])
                          : bih[2 * Hn + jA];
            // s==1 (hh), k>=89: zero — b_hn handled as register fma
          }
          f[e] = (bf16)v;
        }
        Bf[g][s][kt] = f;
      }
    }

  float bhnq[4];
#pragma unroll
  for (int q = 0; q < 4; ++q)
    bhnq[q] = (j0 + q < Hn) ? bhh[2 * Hn + j0 + q] : 0.f;

  // ---- X staging: 128 rows x 12 chunks of 8 f32; exactly 2 chunks/thread ----
  int soff0, soff1, loff0, loff1;
  bool lst0, lst1;
  {
    const int p0 = tid, p1 = tid + NTHR;
    const int r0 = p0 / 12, s0 = p0 - r0 * 12;
    const int r1 = p1 / 12, s1 = p1 - r1 * 12;
    lst0 = (s0 == 11); lst1 = (s1 == 11);
    soff0 = r0 * (Tn * Hn) + s0 * 8;  loff0 = r0 * LDP + s0 * 8;
    soff1 = r1 * (Tn * Hn) + s1 * 8;  loff1 = r1 * LDP + s1 * 8;
  }
  const float* Xb2 = X + brow0 * (size_t)(Tn * Hn);
  f32x4 A0, B0, A1, B1;

  auto issue = [&](int toff) {
    const float* p0 = Xb2 + soff0 + toff;
    const float* p1 = Xb2 + soff1 + toff;
    if (lst0) { f32x4 a = {p0[0], 1.0f, 0.f, 0.f}; A0 = a; B0 = (f32x4){0.f,0.f,0.f,0.f}; }
    else      { A0 = ld4(p0); B0 = ld4(p0 + 4); }
    if (lst1) { f32x4 a = {p1[0], 1.0f, 0.f, 0.f}; A1 = a; B1 = (f32x4){0.f,0.f,0.f,0.f}; }
    else      { A1 = ld4(p1); B1 = ld4(p1 + 4); }
  };
  auto commit = [&](int plane) {
    *(bf16x8*)(&Xl[plane][0][0] + loff0) = pack8(A0, B0);
    *(bf16x8*)(&Xl[plane][0][0] + loff1) = pack8(A1, B1);
  };

  float hold[4][4];
#pragma unroll
  for (int mt = 0; mt < 4; ++mt)
#pragma unroll
    for (int q = 0; q < 4; ++q) hold[mt][q] = 0.f;

  // lane-constant LDS bases
  bf16*       hwb = &Hl[0][0][0] + (hf * 64 + l15) * LDP + j0;      // b64 write
  const bf16* xrb = &Xl[0][0][0] + (hf * 64 + l15) * LDP + kg * 8;  // B-frag reads
  const bf16* hrb = &Hl[0][0][0] + (hf * 64 + l15) * LDP + kg * 8;
  const int bufo = BM * LDP;

  // ---- prologue: h(0)=0 -> plane0 (covers ALL 96 j incl. pads); X(0) -> plane0 ----
  {
    const bf16x4 z4 = {(bf16)0.f, (bf16)0.f, (bf16)0.f, (bf16)0.f};
#pragma unroll
    for (int mt = 0; mt < 4; ++mt)
      *(bf16x4*)(hwb + mt * 16 * LDP) = z4;
  }
  issue(0);
  commit(0);

  int toff = Hn;
  for (int t = 0; t < Tn; ++t) {
    const int b = t & 1;
    __syncthreads();                      // buf b holds X(t), h(t)
    const bool pf = (t + 1 < Tn);
    if (pf) issue(toff);                  // X(t+1): lands under this step

    __builtin_amdgcn_s_setprio(1);
    const bf16* xr = xrb + b * bufo;
    const bf16* hr = hrb + b * bufo;
    bf16*       hw = hwb + (b ^ 1) * bufo;
#pragma unroll
    for (int mt = 0; mt < 4; ++mt) {
      f32x4 ari = {0,0,0,0}, arh = {0,0,0,0};
      f32x4 azi = {0,0,0,0}, azh = {0,0,0,0};
      f32x4 ain = {0,0,0,0}, ahn = {0,0,0,0};
#pragma unroll
      for (int kt = 0; kt < 3; ++kt) {
        const bf16x8 bx = *(const bf16x8*)(xr + mt * 16 * LDP + kt * 32);
        const bf16x8 bh = *(const bf16x8*)(hr + mt * 16 * LDP + kt * 32);
        ari = __builtin_amdgcn_mfma_f32_16x16x32_bf16(Bf[0][0][kt], bx, ari, 0, 0, 0);
        arh = __builtin_amdgcn_mfma_f32_16x16x32_bf16(Bf[0][1][kt], bh, arh, 0, 0, 0);
        azi = __builtin_amdgcn_mfma_f32_16x16x32_bf16(Bf[1][0][kt], bx, azi, 0, 0, 0);
        azh = __builtin_amdgcn_mfma_f32_16x16x32_bf16(Bf[1][1][kt], bh, azh, 0, 0, 0);
        ain = __builtin_amdgcn_mfma_f32_16x16x32_bf16(Bf[2][0][kt], bx, ain, 0, 0, 0);
        ahn = __builtin_amdgcn_mfma_f32_16x16x32_bf16(Bf[2][1][kt], bh, ahn, 0, 0, 0);
      }
      bf16x4 wv4;
#pragma unroll
      for (int q = 0; q < 4; ++q) {
        const float r_ = fsig(ari[q] + arh[q]);
        const float z_ = fsig(azi[q] + azh[q]);
        const float n_ = ftanh(ain[q] + r_ * (ahn[q] + bhnq[q]));
        const float hv = n_ + z_ * (hold[mt][q] - n_);
        hold[mt][q] = hv;
        wv4[q] = (bf16)hv;
      }
      *(bf16x4*)(hw + mt * 16 * LDP) = wv4;   // h(t+1): 4 consecutive j, b64
    }
    __builtin_amdgcn_s_setprio(0);
    if (pf) { commit(b ^ 1); toff += Hn; }   // X(t+1) -> buf b^1
  }
  __syncthreads();   // h(120) (written to plane 0 during t=119) visible

  // ---- epilogue: metric_fc (89->32, sigmoid), output_fc (32->1, sigmoid) ----
  for (int p = tid; p < BM * 32; p += NTHR) {
    const int r = p >> 5, c = p & 31;
    const bf16* hr2 = &Hl[0][r][0];          // plain row-major final h
    const float* wrow = Wm + c * Hn;
    float acc = bm[c];
#pragma unroll 4
    for (int cb = 0; cb < 11; ++cb) {
      const bf16x8 hv = *(const bf16x8*)(hr2 + cb * 8);
      const f32x4 wa = ld4(wrow + cb * 8);
      const f32x4 wb = ld4(wrow + cb * 8 + 4);
      acc = fmaf((float)hv[0], wa[0], acc); acc = fmaf((float)hv[1], wa[1], acc);
      acc = fmaf((float)hv[2], wa[2], acc); acc = fmaf((float)hv[3], wa[3], acc);
      acc = fmaf((float)hv[4], wb[0], acc); acc = fmaf((float)hv[5], wb[1], acc);
      acc = fmaf((float)hv[6], wb[2], acc); acc = fmaf((float)hv[7], wb[3], acc);
    }
    acc = fmaf((float)hr2[88], wrow[88], acc);   // k=88
    const float mv = fsig(acc);
    Ml[r][c] = mv;
    Y[(size_t)Bt + (brow0 + r) * 32 + c] = mv;   // out_mmetric
  }
  __syncthreads();
  if (tid < BM) {
    float acc = bo[0];
#pragma unroll
    for (int c = 0; c < 32; ++c) acc = fmaf(Ml[tid][c], Wo[c], acc);
    Y[brow0 + tid] = fsig(acc);                  // out_mscore
  }
}

extern "C" void kernel_launch(void* const* d_in, const int* in_sizes, int n_in,
                              void* d_out, int out_size, void* d_ws, size_t ws_size,
                              hipStream_t stream) {
  const float* X   = (const float*)d_in[0];
  const float* Wih = (const float*)d_in[1];
  const float* Whh = (const float*)d_in[2];
  const float* bih = (const float*)d_in[3];
  const float* bhh = (const float*)d_in[4];
  const float* Wm  = (const float*)d_in[5];
  const float* bm  = (const float*)d_in[6];
  const float* Wo  = (const float*)d_in[7];
  const float* bo  = (const float*)d_in[8];

  const int B = in_sizes[0] / (Tn * Hn);   // 32768
  dim3 grid(B / BM), block(NTHR);
  gru_fused<<<grid, block, 0, stream>>>(X, Wih, Whh, bih, bhh, Wm, bm, Wo, bo,
                                        (float*)d_out, B);
}

// Round 8
// 612.199 us; speedup vs baseline: 1.0250x; 1.0250x over previous
//
#include <hip/hip_runtime.h>
#include <hip/hip_bf16.h>

#define Hn   89
#define Tn   120
#define BM   128
#define LDP  104   // bf16 pitch: 208B rows, 16B-aligned; quad-balanced b128 access
#define NTHR 768   // 12 waves = 6 j-slices x 2 row-halves; grid=256 -> 1 block/CU

using bf16   = __bf16;
using bf16x4 = __attribute__((ext_vector_type(4))) __bf16;
using bf16x8 = __attribute__((ext_vector_type(8))) __bf16;
typedef __attribute__((ext_vector_type(4))) float f32x4;

#define SRZ (-1.44269504f)   // r/z pre-scale: sig(x) = rcp(1+exp2(-log2e*x))
#define SNN ( 2.88539008f)   // n pre-scale: tanh(x) = 1-2*rcp(1+exp2(2log2e*x))

__device__ __forceinline__ f32x4 ld4(const float* p) {   // 4B-aligned 16B load
  f32x4 v; __builtin_memcpy(&v, p, 16); return v;
}
__device__ __forceinline__ bf16x8 pack8(f32x4 a, f32x4 b) {
  bf16x8 r;
  r[0]=(bf16)a[0]; r[1]=(bf16)a[1]; r[2]=(bf16)a[2]; r[3]=(bf16)a[3];
  r[4]=(bf16)b[0]; r[5]=(bf16)b[1]; r[6]=(bf16)b[2]; r[7]=(bf16)b[3];
  return r;
}
__device__ __forceinline__ float fsig(float x) {   // epilogue only (unscaled)
  return __builtin_amdgcn_rcpf(1.f + __builtin_amdgcn_exp2f(-1.44269504f * x));
}

// Persistent block: 128 rows x 120 steps, 12 waves (6 j-slices x 2 row-halves).
// Swapped-operand MFMA (A=weights, B=X/H): lane owns 4 consecutive j for one
// batch row -> h-write is one aligned ds_write_b64 per row-tile; H row-major.
// 2-DEEP X staging: step t does { BAR; commit X(t+1) (regs loaded at t-1);
// issue X(t+2); compute from plane t&1; h -> plane t&1^1 }. Global-load
// latency tails get a full step of slack -> no barrier convoy from VMEM.
// Activation input scales folded into weights (SRZ/SNN): gates are pure
// rcp(1+exp2(acc)) forms. Biases via X col89==1.0; b_hn as register fma.
__global__ __launch_bounds__(NTHR, 3)
void gru_fused(const float* __restrict__ X,    // [B][T][89]
               const float* __restrict__ Wih,  // [267][89]
               const float* __restrict__ Whh,  // [267][89]
               const float* __restrict__ bih,  // [267]
               const float* __restrict__ bhh,  // [267]
               const float* __restrict__ Wm,   // [32][89]
               const float* __restrict__ bm,   // [32]
               const float* __restrict__ Wo,   // [32]
               const float* __restrict__ bo,   // [1]
               float* __restrict__ Y,          // [B] mscore | [B][32] mmetric
               int Bt)
{
  __shared__ __align__(16) bf16 Xl[2][BM][LDP];
  __shared__ __align__(16) bf16 Hl[2][BM][LDP];
  __shared__ float Ml[BM][32];

  const int tid  = threadIdx.x;
  const int lane = tid & 63;
  const int wv   = tid >> 6;       // 0..11
  const int jt   = wv >> 1;        // j-slice 0..5
  const int hf   = wv & 1;         // row half
  const int l15  = lane & 15;
  const int kg   = lane >> 4;      // 0..3
  const int jA   = jt * 16 + l15;  // A-frag row (j) for weight loads
  const bool jAok = (jA < Hn);
  const int j0   = jt * 16 + kg * 4;  // this lane's 4 output j's
  const size_t brow0 = (size_t)blockIdx.x * BM;

  // ---- weights -> persistent A-frags; ih k==89 carries biases; pre-scaled ----
  bf16x8 Bf[3][2][3];  // [gate r/z/n][ih/hh][k-tile]
#pragma unroll
  for (int g = 0; g < 3; ++g)
#pragma unroll
    for (int s = 0; s < 2; ++s) {
      const float* W = s ? Whh : Wih;
      const float sc = (g < 2) ? SRZ : SNN;
#pragma unroll
      for (int kt = 0; kt < 3; ++kt) {
        bf16x8 f;
        const int k0 = kt * 32 + kg * 8;
#pragma unroll
        for (int e = 0; e < 8; ++e) {
          const int k = k0 + e;
          float v = 0.f;
          if (jAok) {
            if (k < Hn) v = sc * W[(size_t)(g * Hn + jA) * Hn + k];
            else if (k == Hn && s == 0)   // pairs with X col89 == 1.0
              v = (g < 2) ? sc * (bih[g * Hn + jA] + bhh[g * Hn + jA])
                          : sc * bih[2 * Hn + jA];
          }
          f[e] = (bf16)v;
        }
        Bf[g][s][kt] = f;
      }
    }

  float bhnq[4];
#pragma unroll
  for (int q = 0; q < 4; ++q)
    bhnq[q] = (j0 + q < Hn) ? SNN * bhh[2 * Hn + j0 + q] : 0.f;

  // ---- X staging: 128 rows x 12 chunks of 8 f32; exactly 2 chunks/thread ----
  int soff0, soff1, loff0, loff1;
  bool lst0, lst1;
  {
    const int p0 = tid, p1 = tid + NTHR;
    const int r0 = p0 / 12, s0 = p0 - r0 * 12;
    const int r1 = p1 / 12, s1 = p1 - r1 * 12;
    lst0 = (s0 == 11); lst1 = (s1 == 11);
    soff0 = r0 * (Tn * Hn) + s0 * 8;  loff0 = r0 * LDP + s0 * 8;
    soff1 = r1 * (Tn * Hn) + s1 * 8;  loff1 = r1 * LDP + s1 * 8;
  }
  const float* Xb2 = X + brow0 * (size_t)(Tn * Hn);
  f32x4 A0, B0, A1, B1;

  auto issue = [&](int toff) {
    const float* p0 = Xb2 + soff0 + toff;
    const float* p1 = Xb2 + soff1 + toff;
    if (lst0) { f32x4 a = {p0[0], 1.0f, 0.f, 0.f}; A0 = a; B0 = (f32x4){0.f,0.f,0.f,0.f}; }
    else      { A0 = ld4(p0); B0 = ld4(p0 + 4); }
    if (lst1) { f32x4 a = {p1[0], 1.0f, 0.f, 0.f}; A1 = a; B1 = (f32x4){0.f,0.f,0.f,0.f}; }
    else      { A1 = ld4(p1); B1 = ld4(p1 + 4); }
  };
  auto commit = [&](int plane) {
    *(bf16x8*)(&Xl[plane][0][0] + loff0) = pack8(A0, B0);
    *(bf16x8*)(&Xl[plane][0][0] + loff1) = pack8(A1, B1);
  };

  float hold[4][4];
#pragma unroll
  for (int mt = 0; mt < 4; ++mt)
#pragma unroll
    for (int q = 0; q < 4; ++q) hold[mt][q] = 0.f;

  // lane-constant LDS bases
  bf16*       hwb = &Hl[0][0][0] + (hf * 64 + l15) * LDP + j0;      // b64 write
  const bf16* xrb = &Xl[0][0][0] + (hf * 64 + l15) * LDP + kg * 8;  // B-frag reads
  const bf16* hrb = &Hl[0][0][0] + (hf * 64 + l15) * LDP + kg * 8;
  const int bufo = BM * LDP;

  // ---- prologue: X(0)->plane0; h(0)=0 -> plane0; X(1) in regs ----
  issue(0);
  commit(0);
  {
    const bf16x4 z4 = {(bf16)0.f, (bf16)0.f, (bf16)0.f, (bf16)0.f};
#pragma unroll
    for (int mt = 0; mt < 4; ++mt)
      *(bf16x4*)(hwb + mt * 16 * LDP) = z4;
  }
  issue(Hn);

  int toff = 2 * Hn;
  for (int t = 0; t < Tn; ++t) {
    const int b = t & 1;
    __syncthreads();                      // plane b holds X(t), h(t)
    if (t + 1 < Tn) commit(b ^ 1);        // X(t+1) -> plane b^1 (regs from t-1)
    if (t + 2 < Tn) { issue(toff); toff += Hn; }   // X(t+2): full step of slack

    __builtin_amdgcn_s_setprio(1);
    const bf16* xr = xrb + b * bufo;
    const bf16* hr = hrb + b * bufo;
    bf16*       hw = hwb + (b ^ 1) * bufo;
#pragma unroll
    for (int mt = 0; mt < 4; ++mt) {
      f32x4 ari = {0,0,0,0}, arh = {0,0,0,0};
      f32x4 azi = {0,0,0,0}, azh = {0,0,0,0};
      f32x4 ain = {0,0,0,0}, ahn = {0,0,0,0};
#pragma unroll
      for (int kt = 0; kt < 3; ++kt) {
        const bf16x8 bx = *(const bf16x8*)(xr + mt * 16 * LDP + kt * 32);
        const bf16x8 bh = *(const bf16x8*)(hr + mt * 16 * LDP + kt * 32);
        ari = __builtin_amdgcn_mfma_f32_16x16x32_bf16(Bf[0][0][kt], bx, ari, 0, 0, 0);
        arh = __builtin_amdgcn_mfma_f32_16x16x32_bf16(Bf[0][1][kt], bh, arh, 0, 0, 0);
        azi = __builtin_amdgcn_mfma_f32_16x16x32_bf16(Bf[1][0][kt], bx, azi, 0, 0, 0);
        azh = __builtin_amdgcn_mfma_f32_16x16x32_bf16(Bf[1][1][kt], bh, azh, 0, 0, 0);
        ain = __builtin_amdgcn_mfma_f32_16x16x32_bf16(Bf[2][0][kt], bx, ain, 0, 0, 0);
        ahn = __builtin_amdgcn_mfma_f32_16x16x32_bf16(Bf[2][1][kt], bh, ahn, 0, 0, 0);
      }
      bf16x4 wv4;
#pragma unroll
      for (int q = 0; q < 4; ++q) {
        const float r_ = __builtin_amdgcn_rcpf(1.f + __builtin_amdgcn_exp2f(ari[q] + arh[q]));
        const float z_ = __builtin_amdgcn_rcpf(1.f + __builtin_amdgcn_exp2f(azi[q] + azh[q]));
        const float s_ = ain[q] + r_ * (ahn[q] + bhnq[q]);
        const float n_ = fmaf(-2.f, __builtin_amdgcn_rcpf(1.f + __builtin_amdgcn_exp2f(s_)), 1.f);
        const float hv = n_ + z_ * (hold[mt][q] - n_);
        hold[mt][q] = hv;
        wv4[q] = (bf16)hv;
      }
      *(bf16x4*)(hw + mt * 16 * LDP) = wv4;   // h(t+1): 4 consecutive j, b64
    }
    __builtin_amdgcn_s_setprio(0);
  }
  __syncthreads();   // h(120) (written to plane 0 during t=119) visible

  // ---- epilogue: metric_fc (89->32, sigmoid), output_fc (32->1, sigmoid) ----
  for (int p = tid; p < BM * 32; p += NTHR) {
    const int r = p >> 5, c = p & 31;
    const bf16* hr2 = &Hl[0][r][0];          // plain row-major final h
    const float* wrow = Wm + c * Hn;
    float acc = bm[c];
#pragma unroll 4
    for (int cb = 0; cb < 11; ++cb) {
      const bf16x8 hv = *(const bf16x8*)(hr2 + cb * 8);
      const f32x4 wa = ld4(wrow + cb * 8);
      const f32x4 wb = ld4(wrow + cb * 8 + 4);
      acc = fmaf((float)hv[0], wa[0], acc); acc = fmaf((float)hv[1], wa[1], acc);
      acc = fmaf((float)hv[2], wa[2], acc); acc = fmaf((float)hv[3], wa[3], acc);
      acc = fmaf((float)hv[4], wb[0], acc); acc = fmaf((float)hv[5], wb[1], acc);
      acc = fmaf((float)hv[6], wb[2], acc); acc = fmaf((float)hv[7], wb[3], acc);
    }
    acc = fmaf((float)hr2[88], wrow[88], acc);   // k=88
    const float mv = fsig(acc);
    Ml[r][c] = mv;
    Y[(size_t)Bt + (brow0 + r) * 32 + c] = mv;   // out_mmetric
  }
  __syncthreads();
  if (tid < BM) {
    float acc = bo[0];
#pragma unroll
    for (int c = 0; c < 32; ++c) acc = fmaf(Ml[tid][c], Wo[c], acc);
    Y[brow0 + tid] = fsig(acc);                  // out_mscore
  }
}

extern "C" void kernel_launch(void* const* d_in, const int* in_sizes, int n_in,
                              void* d_out, int out_size, void* d_ws, size_t ws_size,
                              hipStream_t stream) {
  const float* X   = (const float*)d_in[0];
  const float* Wih = (const float*)d_in[1];
  const float* Whh = (const float*)d_in[2];
  const float* bih = (const float*)d_in[3];
  const float* bhh = (const float*)d_in[4];
  const float* Wm  = (const float*)d_in[5];
  const float* bm  = (const float*)d_in[6];
  const float* Wo  = (const float*)d_in[7];
  const float* bo  = (const float*)d_in[8];

  const int B = in_sizes[0] / (Tn * Hn);   // 32768
  dim3 grid(B / BM), block(NTHR);
  gru_fused<<<grid, block, 0, stream>>>(X, Wih, Whh, bih, bhh, Wm, bm, Wo, bo,
                                        (float*)d_out, B);
}